// Round 10
// baseline (204.411 us; speedup 1.0000x reference)
//
#include <hip/hip_runtime.h>
#include <hip/hip_bf16.h>

#define N_NODES 100000
#define N_EDGES 1600000
#define F_IN 128
#define HID 64
#define NC 10

#define BSH 7
#define BNODES 128                       // nodes per bucket = 1<<BSH
#define NB 782                           // ceil(N_NODES / 128)
#define CAP 2560                         // padded bucket capacity (λ=2048, +11σ)
#define PBLK 256                         // partition blocks
#define TILE ((N_EDGES + PBLK - 1) / PBLK)  // 6250 edges per block

#define XROWS 64
#define XPAD 132                         // 528 B row: 16B-aligned, 2-way banks (free)

__device__ __forceinline__ unsigned short f2bf(float f) {
    unsigned u = __float_as_uint(f);
    u += 0x7FFFu + ((u >> 16) & 1u);     // round-to-nearest-even
    return (unsigned short)(u >> 16);
}
__device__ __forceinline__ float bf2f(unsigned short b) {
    return __uint_as_float(((unsigned)b) << 16);
}

// ---------------- init: bcursor[b] = b*CAP
__global__ void k_init(int* __restrict__ bcursor) {
    int b = blockIdx.x * blockDim.x + threadIdx.x;
    if (b < NB) bcursor[b] = b * CAP;
}

// ---------------- s3: partition edges into padded bucket regions
// ppair entry = src | (local_dst << 20)
__global__ __launch_bounds__(256) void s3_part(const int* __restrict__ src,
                                               const int* __restrict__ dst,
                                               int* __restrict__ bcursor,
                                               unsigned* __restrict__ ppair) {
    __shared__ int lh[NB];     // histogram, then running cursor
    int t = threadIdx.x;
    for (int k = t; k < NB; k += 256) lh[k] = 0;
    __syncthreads();
    int b0 = blockIdx.x * TILE;
    int b1 = b0 + TILE < N_EDGES ? b0 + TILE : N_EDGES;
    for (int i = b0 + t; i < b1; i += 256)
        atomicAdd(&lh[dst[i] >> BSH], 1);
    __syncthreads();
    for (int k = t; k < NB; k += 256) {
        int c = lh[k];
        lh[k] = c ? atomicAdd(&bcursor[k], c) : 0;   // coalesced, with return
    }
    __syncthreads();
    for (int i = b0 + t; i < b1; i += 256) {
        int d = dst[i];
        int slot = atomicAdd(&lh[d >> BSH], 1);      // LDS atomic (fast)
        ppair[slot] = (unsigned)src[i] | ((unsigned)(d & (BNODES - 1)) << 20);
    }
}

// ---------------- s4: per-bucket CSR finalize (row_info, dis, padded csr)
__global__ __launch_bounds__(256) void s4_build(const unsigned* __restrict__ ppair,
                                                const int* __restrict__ bcursor,
                                                int2* __restrict__ row_info,
                                                float* __restrict__ dis,
                                                int* __restrict__ csr) {
    __shared__ int h[BNODES];
    __shared__ int sc[BNODES];
    __shared__ int lcur[BNODES];
    int t = threadIdx.x;
    int b = blockIdx.x;
    int base = b * CAP;
    int cnt = bcursor[b] - base;
    int nodes0 = b << BSH;
    if (t < BNODES) h[t] = 0;
    __syncthreads();
    for (int j = t; j < cnt; j += 256)
        atomicAdd(&h[ppair[base + j] >> 20], 1);
    __syncthreads();
    if (t < BNODES) sc[t] = h[t];
    __syncthreads();
    for (int off = 1; off < BNODES; off <<= 1) {
        int u = (t < BNODES && t >= off) ? sc[t - off] : 0;
        __syncthreads();
        if (t < BNODES) sc[t] += u;
        __syncthreads();
    }
    if (t < BNODES) {
        int node = nodes0 + t;
        int excl = sc[t] - h[t];
        if (node < N_NODES) {
            row_info[node] = make_int2(base + excl, h[t]);
            dis[node] = rsqrtf((float)(h[t] + 1));
            lcur[t] = base + excl;
        }
    }
    __syncthreads();
    for (int j = t; j < cnt; j += 256) {
        unsigned p = ppair[base + j];
        int slot = atomicAdd(&lcur[p >> 20], 1);        // LDS atomic
        csr[slot] = (int)(p & 0xFFFFFu);
    }
}

__device__ __forceinline__ float4 fma4(float s, float4 w, float4 a) {
    a.x = fmaf(s, w.x, a.x);
    a.y = fmaf(s, w.y, a.y);
    a.z = fmaf(s, w.z, a.z);
    a.w = fmaf(s, w.w, a.w);
    return a;
}

// ---------------- hxs = bf16((x @ W1) * dis) ; 64x64 LDS-tiled, 4x4 per thread
__global__ __launch_bounds__(256) void k_xw(const float* __restrict__ x,
                                            const float* __restrict__ W1,
                                            const float* __restrict__ dis,
                                            unsigned short* __restrict__ hxs) {
    __shared__ float Ws[F_IN * HID];      // 32 KB, [k][c] (== W1 layout)
    __shared__ float Xs[XROWS * XPAD];    // 33 KB, [n][k] padded
    int t = threadIdx.x;
    int base = blockIdx.x * XROWS;

    for (int i = t; i < (F_IN * HID) / 4; i += 256)
        reinterpret_cast<float4*>(Ws)[i] = reinterpret_cast<const float4*>(W1)[i];

    for (int i = t; i < XROWS * (F_IN / 4); i += 256) {
        int n = i >> 5;           // 32 float4 per row
        int kq = i & 31;
        int gn = base + n;
        float4 v = make_float4(0.f, 0.f, 0.f, 0.f);
        if (gn < N_NODES)
            v = reinterpret_cast<const float4*>(x + (size_t)gn * F_IN)[kq];
        *reinterpret_cast<float4*>(&Xs[n * XPAD + kq * 4]) = v;
    }
    __syncthreads();

    int cg = (t & 15) * 4;        // col base: 16 groups x 4 cols
    int ng = (t >> 4) * 4;        // node base: 16 groups x 4 nodes
    float4 a0 = make_float4(0.f, 0.f, 0.f, 0.f);
    float4 a1 = a0, a2 = a0, a3 = a0;

#pragma unroll 4
    for (int k0 = 0; k0 < F_IN; k0 += 4) {
        float4 w0 = *reinterpret_cast<const float4*>(&Ws[(k0 + 0) * HID + cg]);
        float4 w1 = *reinterpret_cast<const float4*>(&Ws[(k0 + 1) * HID + cg]);
        float4 w2 = *reinterpret_cast<const float4*>(&Ws[(k0 + 2) * HID + cg]);
        float4 w3 = *reinterpret_cast<const float4*>(&Ws[(k0 + 3) * HID + cg]);
        float4 x0 = *reinterpret_cast<const float4*>(&Xs[(ng + 0) * XPAD + k0]);
        float4 x1 = *reinterpret_cast<const float4*>(&Xs[(ng + 1) * XPAD + k0]);
        float4 x2 = *reinterpret_cast<const float4*>(&Xs[(ng + 2) * XPAD + k0]);
        float4 x3 = *reinterpret_cast<const float4*>(&Xs[(ng + 3) * XPAD + k0]);
        a0 = fma4(x0.x, w0, a0); a0 = fma4(x0.y, w1, a0);
        a0 = fma4(x0.z, w2, a0); a0 = fma4(x0.w, w3, a0);
        a1 = fma4(x1.x, w0, a1); a1 = fma4(x1.y, w1, a1);
        a1 = fma4(x1.z, w2, a1); a1 = fma4(x1.w, w3, a1);
        a2 = fma4(x2.x, w0, a2); a2 = fma4(x2.y, w1, a2);
        a2 = fma4(x2.z, w2, a2); a2 = fma4(x2.w, w3, a2);
        a3 = fma4(x3.x, w0, a3); a3 = fma4(x3.y, w1, a3);
        a3 = fma4(x3.z, w2, a3); a3 = fma4(x3.w, w3, a3);
    }

    int n0 = base + ng;
    if (n0 + 0 < N_NODES) {
        float d = dis[n0 + 0];
        ushort4 o; o.x = f2bf(a0.x * d); o.y = f2bf(a0.y * d);
        o.z = f2bf(a0.z * d); o.w = f2bf(a0.w * d);
        *reinterpret_cast<ushort4*>(&hxs[(size_t)(n0 + 0) * HID + cg]) = o;
    }
    if (n0 + 1 < N_NODES) {
        float d = dis[n0 + 1];
        ushort4 o; o.x = f2bf(a1.x * d); o.y = f2bf(a1.y * d);
        o.z = f2bf(a1.z * d); o.w = f2bf(a1.w * d);
        *reinterpret_cast<ushort4*>(&hxs[(size_t)(n0 + 1) * HID + cg]) = o;
    }
    if (n0 + 2 < N_NODES) {
        float d = dis[n0 + 2];
        ushort4 o; o.x = f2bf(a2.x * d); o.y = f2bf(a2.y * d);
        o.z = f2bf(a2.z * d); o.w = f2bf(a2.w * d);
        *reinterpret_cast<ushort4*>(&hxs[(size_t)(n0 + 2) * HID + cg]) = o;
    }
    if (n0 + 3 < N_NODES) {
        float d = dis[n0 + 3];
        ushort4 o; o.x = f2bf(a3.x * d); o.y = f2bf(a3.y * d);
        o.z = f2bf(a3.z * d); o.w = f2bf(a3.w * d);
        *reinterpret_cast<ushort4*>(&hxs[(size_t)(n0 + 3) * HID + cg]) = o;
    }
}

// ---------------- fused layer-1 aggregate + bias + relu + W2 + scale -> bf16 h2s
// One wave per node. 4 groups of 16 lanes; each group = one edge; lane&15 = qi
// (uint2 column quad). 4 edges per load instr via global_load_dwordx2 (saddr).
__global__ __launch_bounds__(256) void k_agg1f(const int2* __restrict__ row_info,
                                               const float* __restrict__ dis,
                                               const unsigned short* __restrict__ hxs,
                                               const int* __restrict__ csr,
                                               const float* __restrict__ b1,
                                               const float* __restrict__ W2,
                                               unsigned short* __restrict__ h2s) {
    int lane = threadIdx.x & 63;
    int node = (blockIdx.x * blockDim.x + threadIdx.x) >> 6;
    if (node >= N_NODES) return;
    int qi  = lane & 15;          // uint2 index within row (16 x 8B = 128B)
    int grp = lane >> 4;          // edge slot 0..3
    unsigned qoff = (unsigned)qi * 8u;
    const char* hb = reinterpret_cast<const char*>(hxs);

    int2 ri = row_info[node];
    int beg = ri.x, m = ri.y;
    float dn = dis[node];         // hoist early

    float ax = 0.f, ay = 0.f, az = 0.f, aw = 0.f;
    int j = 0;
    int mmain = m & ~7;
    for (; j < mmain; j += 8) {   // 8 edges per iter (2 rounds of 4)
        int e0 = csr[beg + j + grp];
        int e1 = csr[beg + j + 4 + grp];
        unsigned v0 = ((unsigned)e0 << 7) + qoff;
        unsigned v1 = ((unsigned)e1 << 7) + qoff;
        uint2 u0 = *reinterpret_cast<const uint2*>(hb + v0);
        uint2 u1 = *reinterpret_cast<const uint2*>(hb + v1);
        ax += __uint_as_float(u0.x << 16); ay += __uint_as_float(u0.x & 0xffff0000u);
        az += __uint_as_float(u0.y << 16); aw += __uint_as_float(u0.y & 0xffff0000u);
        ax += __uint_as_float(u1.x << 16); ay += __uint_as_float(u1.x & 0xffff0000u);
        az += __uint_as_float(u1.y << 16); aw += __uint_as_float(u1.y & 0xffff0000u);
    }
    if (j < m) {                  // predicated round 1 (4 edges)
        int idx = j + grp;
        bool v = idx < m;
        int e = csr[beg + (v ? idx : 0)];
        uint2 u = *reinterpret_cast<const uint2*>(hb + (((unsigned)e << 7) + qoff));
        ax += v ? __uint_as_float(u.x << 16) : 0.f;
        ay += v ? __uint_as_float(u.x & 0xffff0000u) : 0.f;
        az += v ? __uint_as_float(u.y << 16) : 0.f;
        aw += v ? __uint_as_float(u.y & 0xffff0000u) : 0.f;
        j += 4;
        if (j < m) {              // predicated round 2 (remaining <4)
            int idx2 = j + grp;
            bool v2 = idx2 < m;
            int e2 = csr[beg + (v2 ? idx2 : 0)];
            uint2 u2 = *reinterpret_cast<const uint2*>(hb + (((unsigned)e2 << 7) + qoff));
            ax += v2 ? __uint_as_float(u2.x << 16) : 0.f;
            ay += v2 ? __uint_as_float(u2.x & 0xffff0000u) : 0.f;
            az += v2 ? __uint_as_float(u2.y << 16) : 0.f;
            aw += v2 ? __uint_as_float(u2.y & 0xffff0000u) : 0.f;
        }
    }
    // merge the 4 edge groups (lane bits 4,5)
    ax += __shfl_xor(ax, 16); ay += __shfl_xor(ay, 16);
    az += __shfl_xor(az, 16); aw += __shfl_xor(aw, 16);
    ax += __shfl_xor(ax, 32); ay += __shfl_xor(ay, 32);
    az += __shfl_xor(az, 32); aw += __shfl_xor(aw, 32);
    // self message (same for all groups)
    uint2 us = *reinterpret_cast<const uint2*>(hb + (((unsigned)node << 7) + qoff));
    ax += __uint_as_float(us.x << 16); ay += __uint_as_float(us.x & 0xffff0000u);
    az += __uint_as_float(us.y << 16); aw += __uint_as_float(us.y & 0xffff0000u);

    // redistribute 4-col/lane (16-lane domain) -> 2-col/lane (32-lane domain)
    int c2 = lane & 31;                    // col pair index: cols {2c2, 2c2+1}
    int srcq = c2 >> 1;
    bool oddp = (c2 & 1) != 0;
    float bx_e = __shfl(ax, srcq), bx_o = __shfl(az, srcq);
    float by_e = __shfl(ay, srcq), by_o = __shfl(aw, srcq);
    float bx = oddp ? bx_o : bx_e;
    float by = oddp ? by_o : by_e;

    float2 lb = *reinterpret_cast<const float2*>(b1 + 2 * c2);
    float vx = bx * dn + lb.x; vx = vx > 0.f ? vx : 0.f;
    float vy = by * dn + lb.y; vy = vy > 0.f ? vy : 0.f;

    // W2 rows 2c2, 2c2+1 = 20 contiguous floats = 5 float4 loads
    const float4* wq = reinterpret_cast<const float4*>(W2 + c2 * 20);
    float4 q0 = wq[0], q1 = wq[1], q2 = wq[2], q3 = wq[3], q4 = wq[4];
    float s0 = vx * q0.x + vy * q2.z;
    float s1 = vx * q0.y + vy * q2.w;
    float s2 = vx * q0.z + vy * q3.x;
    float s3 = vx * q0.w + vy * q3.y;
    float s4 = vx * q1.x + vy * q3.z;
    float s5 = vx * q1.y + vy * q3.w;
    float s6 = vx * q1.z + vy * q4.x;
    float s7 = vx * q1.w + vy * q4.y;
    float s8 = vx * q2.x + vy * q4.z;
    float s9 = vx * q2.y + vy * q4.w;
#pragma unroll
    for (int off = 16; off >= 1; off >>= 1) {     // 5 rounds over 32-lane halves
        s0 += __shfl_xor(s0, off); s1 += __shfl_xor(s1, off);
        s2 += __shfl_xor(s2, off); s3 += __shfl_xor(s3, off);
        s4 += __shfl_xor(s4, off); s5 += __shfl_xor(s5, off);
        s6 += __shfl_xor(s6, off); s7 += __shfl_xor(s7, off);
        s8 += __shfl_xor(s8, off); s9 += __shfl_xor(s9, off);
    }
    float o = s0;
    o = (lane == 1) ? s1 : o; o = (lane == 2) ? s2 : o;
    o = (lane == 3) ? s3 : o; o = (lane == 4) ? s4 : o;
    o = (lane == 5) ? s5 : o; o = (lane == 6) ? s6 : o;
    o = (lane == 7) ? s7 : o; o = (lane == 8) ? s8 : o;
    o = (lane == 9) ? s9 : o;
    if (lane < NC)
        h2s[(size_t)node * NC + lane] = f2bf(o * dn);
}

// ---------------- layer-2 aggregate + bias + log_softmax (bf16 h2s)
// One wave per node; lane&15 = col (10 active), lane>>4 = edge slot (4 in flight)
__global__ __launch_bounds__(256) void k_agg2f(const int2* __restrict__ row_info,
                                               const float* __restrict__ dis,
                                               const unsigned short* __restrict__ h2s,
                                               const int* __restrict__ csr,
                                               const float* __restrict__ b2,
                                               float* __restrict__ out) {
    int lane = threadIdx.x & 63;
    int node = (blockIdx.x * blockDim.x + threadIdx.x) >> 6;
    if (node >= N_NODES) return;
    int c = lane & 15;
    int slot = lane >> 4;
    int cc = c < NC ? c : 0;              // clamped col (avoid OOB reads)
    int2 ri = row_info[node];
    int beg = ri.x, m = ri.y;
    float dn = dis[node];

    float acc = 0.f;
    int j = 0;
    int mmain = m & ~3;
    for (; j < mmain; j += 4) {
        int e = csr[beg + j + slot];
        float v = bf2f(h2s[(size_t)e * NC + cc]);
        acc += v;
    }
    if (j < m) {
        int idx = j + slot;
        bool v = idx < m;
        int e = csr[beg + (v ? idx : 0)];
        float val = bf2f(h2s[(size_t)e * NC + cc]);
        acc += v ? val : 0.f;
    }
    // merge 4 slots (lane bits 4,5)
    acc += __shfl_xor(acc, 16);
    acc += __shfl_xor(acc, 32);
    // self + scale + bias
    acc += bf2f(h2s[(size_t)node * NC + cc]);
    acc = acc * dn + b2[cc];
    float accm = (c < NC) ? acc : -1e30f;
    float mx = accm;
#pragma unroll
    for (int off = 8; off >= 1; off >>= 1)
        mx = fmaxf(mx, __shfl_xor(mx, off, 16));
    float e = (c < NC) ? expf(acc - mx) : 0.f;
    float ssum = e;
#pragma unroll
    for (int off = 8; off >= 1; off >>= 1)
        ssum += __shfl_xor(ssum, off, 16);
    float lse = mx + logf(ssum);
    if (lane < NC) out[(size_t)node * NC + lane] = acc - lse;
}

static inline size_t align16(size_t v) { return (v + 15) & ~(size_t)15; }

extern "C" void kernel_launch(void* const* d_in, const int* in_sizes, int n_in,
                              void* d_out, int out_size, void* d_ws, size_t ws_size,
                              hipStream_t stream) {
    const float* x  = (const float*)d_in[0];
    const int*   ei = (const int*)d_in[1];    // [2, E] int32 (JAX x64 off)
    const float* W1 = (const float*)d_in[2];
    const float* b1 = (const float*)d_in[3];
    const float* W2 = (const float*)d_in[4];
    const float* b2 = (const float*)d_in[5];
    float* out = (float*)d_out;

    const int* src = ei;             // edge_index[0]
    const int* dst = ei + N_EDGES;   // edge_index[1]

    char* ws = (char*)d_ws;
    size_t off = 0;
    int* bcursor = (int*)(ws + off);     off = align16(off + 4u * NB);
    int2* row_info = (int2*)(ws + off);  off = align16(off + 8u * (size_t)N_NODES);   // 0.8 MB
    float* dis = (float*)(ws + off);     off = align16(off + 4u * N_NODES);           // 0.4 MB
    int* csr = (int*)(ws + off);         off = align16(off + 4u * (size_t)NB * CAP);  // 8.0 MB
    unsigned* ppair = (unsigned*)(ws + off);
    off = align16(off + 4u * (size_t)NB * CAP);                                       // 8.0 MB
    unsigned short* hxs = (unsigned short*)(ws + off);
    off = align16(off + 2u * (size_t)N_NODES * HID);                                  // 12.8 MB
    unsigned short* h2s = (unsigned short*)(ws + off);
    off = align16(off + 2u * (size_t)N_NODES * NC);                                   // 2.0 MB

    k_init<<<(NB + 255) / 256, 256, 0, stream>>>(bcursor);
    s3_part<<<PBLK, 256, 0, stream>>>(src, dst, bcursor, ppair);
    s4_build<<<NB, 256, 0, stream>>>(ppair, bcursor, row_info, dis, csr);
    k_xw<<<(N_NODES + XROWS - 1) / XROWS, 256, 0, stream>>>(x, W1, dis, hxs);
    k_agg1f<<<(N_NODES * 64 + 255) / 256, 256, 0, stream>>>(
        row_info, dis, hxs, csr, b1, W2, h2s);
    k_agg2f<<<(N_NODES * 64 + 255) / 256, 256, 0, stream>>>(
        row_info, dis, h2s, csr, b2, out);
}